// Round 4
// baseline (447.157 us; speedup 1.0000x reference)
//
#include <hip/hip_runtime.h>
#include <hip/hip_bf16.h>
#include <hip/hip_cooperative_groups.h>
#include <stdint.h>

namespace cg = cooperative_groups;

#define IN_F 128
#define OUT_F 16
#define NEG_SLOPE 0.2f
#define LB_BITS 7               // bucket = 128 nodes (agg-tile granular)
#define LB_NODES 128
#define NB 782                  // ceil(100000/128)
#define CAP 4608                // per-bucket payload capacity (mean 4092, +8 sigma)
#define SC_E 8192               // edges per scatter block (r1-proven)

// scatter smem layout (bytes)
#define OFF_HIST 0              // int[NB]    = 3128
#define OFF_WSUM 3136           // int[4]     (wave sums for scan)
#define OFF_PREF 3152           // u16[NB+2]  = 1568 -> 4720
#define OFF_GBASE 4720          // u16[NB]    = 1564 -> 6284
#define OFF_SORTP 6400          // u32[SC_E]  = 32768 -> 39168
#define SMEM_FUSED 39168        // 38.25 KB -> 4 blocks/CU

// agg smem layout (overlays same block)
#define AOFF_SORTED 0           // u32[CAP] 18432
#define AOFF_EXS 18432          // f32[CAP] 18432 -> 36864
#define AOFF_HIST 36864         // int[128] -> 37376
#define AOFF_PREF 37376         // -> 37888
#define AOFF_RANK 37888         // -> 38400
#define AOFF_ERS 38400          // f32[128] -> 38912
#define SMEM_AGG 38912

__device__ __forceinline__ float u2f(uint32_t u) {
  union { uint32_t i; float f; } c;
  c.i = u;
  return c.f;
}

// ---------------------------------------------------------------------------
// Scatter: bin 8192 edges into 782 128-node buckets (LDS counting sort),
// reserve global ranges via cursor atomics, write runs coalesced.
// Prefix over 782 buckets = 4 buckets/thread local sum + wave shfl-scan +
// 4 wave offsets (replaces r1's 256-iteration serial LDS walk).
// ---------------------------------------------------------------------------
__device__ __forceinline__ void scatter_phase(
    uint8_t* smem, const int* __restrict__ src, const int* __restrict__ dst,
    int* cursor, uint32_t* payload, int E, int sbid) {
  int t = threadIdx.x;
  int lane = t & 63, wv = t >> 6;
  int* hist = (int*)(smem + OFF_HIST);
  int* wsum = (int*)(smem + OFF_WSUM);
  unsigned short* pref = (unsigned short*)(smem + OFF_PREF);
  unsigned short* gbase = (unsigned short*)(smem + OFF_GBASE);
  uint32_t* sortedP = (uint32_t*)(smem + OFF_SORTP);

  int start = sbid * SC_E;
  int end = min(E, start + SC_E);
  int cnt = end - start;

  for (int i = t; i < NB; i += 256) hist[i] = 0;
  __syncthreads();

  const int4* d4 = (const int4*)(dst + start);
  int n4 = cnt >> 2;
  for (int i = t; i < n4; i += 256) {
    int4 d = d4[i];
    atomicAdd(&hist[d.x >> LB_BITS], 1);
    atomicAdd(&hist[d.y >> LB_BITS], 1);
    atomicAdd(&hist[d.z >> LB_BITS], 1);
    atomicAdd(&hist[d.w >> LB_BITS], 1);
  }
  for (int i = start + (n4 << 2) + t; i < end; i += 256)
    atomicAdd(&hist[dst[i] >> LB_BITS], 1);
  __syncthreads();

  // exclusive prefix: 4 buckets/thread, wave shfl-scan, 4 wave offsets
  int b0 = t * 4;
  int c0 = (b0 < NB) ? hist[b0] : 0;
  int c1 = (b0 + 1 < NB) ? hist[b0 + 1] : 0;
  int c2 = (b0 + 2 < NB) ? hist[b0 + 2] : 0;
  int c3 = (b0 + 3 < NB) ? hist[b0 + 3] : 0;
  int s_loc = c0 + c1 + c2 + c3;
  int inc = s_loc;
#pragma unroll
  for (int off = 1; off < 64; off <<= 1) {
    int v = __shfl_up(inc, off, 64);
    if (lane >= off) inc += v;
  }
  if (lane == 63) wsum[wv] = inc;
  __syncthreads();
  int run = inc - s_loc;
#pragma unroll
  for (int w = 0; w < 4; ++w)
    if (w < wv) run += wsum[w];
  if (b0 < NB) {
    pref[b0] = (unsigned short)run;
    int g = c0 ? atomicAdd(&cursor[b0 * 16], c0) : 0;
    gbase[b0] = (unsigned short)min(g, 65535);
    hist[b0] = 0;
    run += c0;
    if (b0 == NB - 1) pref[NB] = (unsigned short)run;
  }
  if (b0 + 1 < NB) {
    pref[b0 + 1] = (unsigned short)run;
    int g = c1 ? atomicAdd(&cursor[(b0 + 1) * 16], c1) : 0;
    gbase[b0 + 1] = (unsigned short)min(g, 65535);
    hist[b0 + 1] = 0;
    run += c1;
    if (b0 + 1 == NB - 1) pref[NB] = (unsigned short)run;
  }
  if (b0 + 2 < NB) {
    pref[b0 + 2] = (unsigned short)run;
    int g = c2 ? atomicAdd(&cursor[(b0 + 2) * 16], c2) : 0;
    gbase[b0 + 2] = (unsigned short)min(g, 65535);
    hist[b0 + 2] = 0;
    run += c2;
    if (b0 + 2 == NB - 1) pref[NB] = (unsigned short)run;
  }
  if (b0 + 3 < NB) {
    pref[b0 + 3] = (unsigned short)run;
    int g = c3 ? atomicAdd(&cursor[(b0 + 3) * 16], c3) : 0;
    gbase[b0 + 3] = (unsigned short)min(g, 65535);
    hist[b0 + 3] = 0;
    run += c3;
    if (b0 + 3 == NB - 1) pref[NB] = (unsigned short)run;
  }
  __syncthreads();

  // place edges -> sortedP (hist reused as rank, zeroed above)
  const int4* s4 = (const int4*)(src + start);
  for (int i = t; i < n4; i += 256) {
    int4 d = d4[i];
    int4 s = s4[i];
#pragma unroll
    for (int j = 0; j < 4; ++j) {
      int dd = j == 0 ? d.x : j == 1 ? d.y : j == 2 ? d.z : d.w;
      int ss = j == 0 ? s.x : j == 1 ? s.y : j == 2 ? s.z : s.w;
      int b = dd >> LB_BITS;
      int r = atomicAdd(&hist[b], 1);
      sortedP[(int)pref[b] + r] =
          ((uint32_t)ss << LB_BITS) | (uint32_t)(dd & (LB_NODES - 1));
    }
  }
  for (int i = start + (n4 << 2) + t; i < end; i += 256) {
    int dd = dst[i];
    int b = dd >> LB_BITS;
    int r = atomicAdd(&hist[b], 1);
    sortedP[(int)pref[b] + r] =
        ((uint32_t)src[i] << LB_BITS) | (uint32_t)(dd & (LB_NODES - 1));
  }
  __syncthreads();

  // write-out: 16-lane group per bucket run (runs avg ~10.5 entries)
  int g16 = t >> 4, l16 = t & 15;
  for (int b = g16; b < NB; b += 16) {
    int p0 = pref[b];
    int c = (int)pref[b + 1] - p0;
    if (c == 0) continue;
    int gb = gbase[b];
    size_t g0 = (size_t)b * CAP + (size_t)gb;
    for (int j = l16; j < c; j += 16)
      if (gb + j < CAP) payload[g0 + j] = sortedP[p0 + j];
  }
}

// ---------------------------------------------------------------------------
// Projection: 1 thread per node (r1-proven). Streams its 512 B h-row once,
// acc[16] in registers, W chunks read wave-uniform from LDS (broadcast).
// ---------------------------------------------------------------------------
__device__ __forceinline__ void proj_phase(
    uint8_t* smem, const float* __restrict__ h, const float* __restrict__ W,
    const float* __restrict__ a_l, const float* __restrict__ a_r,
    __hip_bfloat16* __restrict__ hWbf, float* __restrict__ el,
    float* __restrict__ er, int N, int pbid) {
  float* Ws = (float*)smem;  // 8 KB
  int t = threadIdx.x;
  for (int i = t; i < OUT_F * IN_F; i += 256) Ws[i] = W[i];
  __syncthreads();

  int node = pbid * 256 + t;
  if (node < N) {
    const float4* hrow = (const float4*)(h + (size_t)node * IN_F);
    float acc[OUT_F];
#pragma unroll
    for (int f = 0; f < OUT_F; ++f) acc[f] = 0.f;

#pragma unroll 4
    for (int k = 0; k < IN_F / 4; ++k) {
      float4 hv = hrow[k];
#pragma unroll
      for (int f = 0; f < OUT_F; ++f) {
        float4 wv = ((const float4*)(Ws + f * IN_F))[k];  // uniform -> bcast
        acc[f] += hv.x * wv.x + hv.y * wv.y + hv.z * wv.z + hv.w * wv.w;
      }
    }

    union {
      unsigned short us[OUT_F];
      uint4 q[2];
    } pk;
#pragma unroll
    for (int f = 0; f < OUT_F; ++f) {
      __hip_bfloat16 b = __float2bfloat16(acc[f]);
      pk.us[f] = *reinterpret_cast<unsigned short*>(&b);
    }
    uint4* dstq = (uint4*)(hWbf + (size_t)node * OUT_F);
    dstq[0] = pk.q[0];
    dstq[1] = pk.q[1];

    float vl = 0.f, vr = 0.f;
#pragma unroll
    for (int f = 0; f < OUT_F; ++f) {
      vl += acc[f] * a_l[f];
      vr += acc[f] * a_r[f];
    }
    el[node] = vl;
    er[node] = vr;
  }
}

// ---------------------------------------------------------------------------
// Aggregation for one 128-node bucket, 256 threads. Pass 1 histograms from
// global (coalesced uint4); pass 3 re-reads L2-hot payload, places into
// sorted[] with leaky+exp fused; pass 4: 2 lanes/node, uint4 (8 bf16) gather.
// ---------------------------------------------------------------------------
__device__ __forceinline__ void agg_phase(
    uint8_t* smem, const uint32_t* __restrict__ payload,
    const int* __restrict__ cursor, const __hip_bfloat16* __restrict__ hWbf,
    const float* __restrict__ el, const float* __restrict__ er,
    float* __restrict__ out, int N, int b) {
  uint32_t* sorted = (uint32_t*)(smem + AOFF_SORTED);
  float* exS = (float*)(smem + AOFF_EXS);
  int* hist = (int*)(smem + AOFF_HIST);
  int* pref = (int*)(smem + AOFF_PREF);
  int* rank = (int*)(smem + AOFF_RANK);
  float* erS = (float*)(smem + AOFF_ERS);

  int t = threadIdx.x;
  size_t base = (size_t)b * CAP;
  int cnt = min(cursor[b * 16], CAP);
  int node0 = b << LB_BITS;

  if (t < LB_NODES) {
    hist[t] = 0;
    rank[t] = 0;
    int nd = node0 + t;
    erS[t] = nd < N ? er[nd] : 0.f;
  }
  __syncthreads();

  // pass 1: histogram straight from global
  const uint4* pay4 = (const uint4*)(payload + base);  // CAP%4==0
  int n4 = (cnt + 3) >> 2;
  for (int i = t; i < n4; i += 256) {
    uint4 v = pay4[i];
    int i0 = i << 2;
    if (i0 + 0 < cnt) atomicAdd(&hist[v.x & (LB_NODES - 1)], 1);
    if (i0 + 1 < cnt) atomicAdd(&hist[v.y & (LB_NODES - 1)], 1);
    if (i0 + 2 < cnt) atomicAdd(&hist[v.z & (LB_NODES - 1)], 1);
    if (i0 + 3 < cnt) atomicAdd(&hist[v.w & (LB_NODES - 1)], 1);
  }
  __syncthreads();

  // pass 2: prefix over 128
  if (t < LB_NODES) {
    int s = 0;
    for (int j = 0; j < t; ++j) s += hist[j];
    pref[t] = s;
  }
  __syncthreads();

  // pass 3: place payload -> sorted with fused leaky+exp
  for (int i = t; i < cnt; i += 256) {
    uint32_t p = payload[base + i];
    int dl = (int)(p & (LB_NODES - 1));
    int r = atomicAdd(&rank[dl], 1);
    int pos = pref[dl] + r;
    sorted[pos] = p;
    float x = el[p >> LB_BITS] + erS[dl];
    x = x > 0.f ? x : NEG_SLOPE * x;
    exS[pos] = __expf(x);
  }
  __syncthreads();

  // pass 4: 2 lanes/node, uint4 (8 bf16) gather, register CSR
  int g = t >> 1, f8 = t & 1;
  int node = node0 + g;
  if (node < N) {
    int k = pref[g];
    int kend = k + hist[g];
    float a0 = 0, a1 = 0, a2 = 0, a3 = 0, a4 = 0, a5 = 0, a6 = 0, a7 = 0,
          es = 0;
    const uint4* hw4 = (const uint4*)hWbf;  // 16 bf16/row = 2 uint4
#pragma unroll 4
    for (; k < kend; ++k) {
      uint32_t p = sorted[k];
      float ex = exS[k];
      uint4 w = hw4[(size_t)(p >> LB_BITS) * 2 + f8];
      a0 += ex * u2f(w.x << 16);
      a1 += ex * u2f(w.x & 0xffff0000u);
      a2 += ex * u2f(w.y << 16);
      a3 += ex * u2f(w.y & 0xffff0000u);
      a4 += ex * u2f(w.z << 16);
      a5 += ex * u2f(w.z & 0xffff0000u);
      a6 += ex * u2f(w.w << 16);
      a7 += ex * u2f(w.w & 0xffff0000u);
      es += ex;
    }
    float inv = 1.0f / fmaxf(es, 1e-16f);
    float4* op = (float4*)(out + (size_t)node * OUT_F + f8 * 8);
    op[0] = make_float4(a0 * inv, a1 * inv, a2 * inv, a3 * inv);
    op[1] = make_float4(a4 * inv, a5 * inv, a6 * inv, a7 * inv);
  }
  __syncthreads();
}

// ---------------------------------------------------------------------------
// Single cooperative kernel: phase0 cursor-zero | scatter+proj | agg.
// Grid = 391 scatter + 391 proj = 782 = NB blocks of 256. Co-residency:
// LDS 38.25 KB -> 4 blocks/CU; launch_bounds(256,4) caps VGPR at 128
// (proj needs ~68) -> capacity 1024 >= 782.
// ---------------------------------------------------------------------------
__global__ __launch_bounds__(256, 4) void gat_fused(
    const float* __restrict__ h, const float* __restrict__ W,
    const float* __restrict__ a_l, const float* __restrict__ a_r,
    const int* __restrict__ src, const int* __restrict__ dst,
    __hip_bfloat16* __restrict__ hWbf, float* __restrict__ el,
    float* __restrict__ er, int* __restrict__ cursor,
    uint32_t* __restrict__ payload, float* __restrict__ out, int N, int E,
    int scatBlocks) {
  __shared__ __align__(16) uint8_t smem[SMEM_FUSED];
  int bid = blockIdx.x, t = threadIdx.x;
  cg::grid_group grid = cg::this_grid();

  // phase 0: zero cursor (replaces hipMemsetAsync dispatch)
  for (int i = bid * 256 + t; i < NB * 16; i += (int)gridDim.x * 256)
    cursor[i] = 0;
  __threadfence();
  grid.sync();

  // phase A: scatter or projection
  if (bid < scatBlocks)
    scatter_phase(smem, src, dst, cursor, payload, E, bid);
  else
    proj_phase(smem, h, W, a_l, a_r, hWbf, el, er, N, bid - scatBlocks);
  __threadfence();
  grid.sync();

  // phase B: one bucket per block
  if (bid < NB)
    agg_phase(smem, payload, cursor, hWbf, el, er, out, N, bid);
}

// ---------------------------------------------------------------------------
// Fallback path (if cooperative launch is rejected, e.g. by graph capture):
// identical device code as the classic 3-dispatch pipeline.
// ---------------------------------------------------------------------------
__global__ __launch_bounds__(256) void ps_kernel(
    const float* __restrict__ h, const float* __restrict__ W,
    const float* __restrict__ a_l, const float* __restrict__ a_r,
    const int* __restrict__ src, const int* __restrict__ dst,
    __hip_bfloat16* __restrict__ hWbf, float* __restrict__ el,
    float* __restrict__ er, int* __restrict__ cursor,
    uint32_t* __restrict__ payload, int N, int E, int scatBlocks) {
  __shared__ __align__(16) uint8_t smem[SMEM_FUSED];
  if ((int)blockIdx.x < scatBlocks)
    scatter_phase(smem, src, dst, cursor, payload, E, blockIdx.x);
  else
    proj_phase(smem, h, W, a_l, a_r, hWbf, el, er, N,
               (int)blockIdx.x - scatBlocks);
}

__global__ __launch_bounds__(256) void agg_kernel(
    const uint32_t* __restrict__ payload, const int* __restrict__ cursor,
    const __hip_bfloat16* __restrict__ hWbf, const float* __restrict__ el,
    const float* __restrict__ er, float* __restrict__ out, int N) {
  __shared__ __align__(16) uint8_t smem[SMEM_AGG];
  agg_phase(smem, payload, cursor, hWbf, el, er, out, N, blockIdx.x);
}

extern "C" void kernel_launch(void* const* d_in, const int* in_sizes, int n_in,
                              void* d_out, int out_size, void* d_ws,
                              size_t ws_size, hipStream_t stream) {
  const float* h = (const float*)d_in[0];
  const int* src = (const int*)d_in[1];
  const int* dst = (const int*)d_in[2];
  const float* W = (const float*)d_in[3];
  const float* a_l = (const float*)d_in[4];
  const float* a_r = (const float*)d_in[5];
  float* out = (float*)d_out;

  int N = in_sizes[0] / IN_F;
  int E = in_sizes[1];
  int scatBlocks = (E + SC_E - 1) / SC_E;       // 391
  int projBlocks = (N + 255) / 256;             // 391
  int grid = scatBlocks + projBlocks;           // 782 (== NB)

  // ws: hWbf (bf16) | el | er | cursor | payload
  __hip_bfloat16* hWbf = (__hip_bfloat16*)d_ws;        // N*16 bf16 = 3.2 MB
  float* el = (float*)(hWbf + (size_t)N * OUT_F);      // N
  float* er = el + N;                                  // N
  int* cursor = (int*)(er + N);                        // NB*16 (line-strided)
  uint32_t* payload = (uint32_t*)(cursor + (size_t)NB * 16);  // NB*CAP

  void* args[] = {&h,  &W,  &a_l,    &a_r,     &src, &dst, &hWbf, &el,
                  &er, &cursor, &payload, &out, &N,   &E,   &scatBlocks};
  hipError_t err = hipLaunchCooperativeKernel((const void*)gat_fused,
                                              dim3(grid), dim3(256), args, 0,
                                              stream);
  if (err != hipSuccess) {
    (void)hipGetLastError();  // clear
    hipMemsetAsync(cursor, 0, (size_t)NB * 16 * sizeof(int), stream);
    ps_kernel<<<grid, 256, 0, stream>>>(h, W, a_l, a_r, src, dst, hWbf, el, er,
                                        cursor, payload, N, E, scatBlocks);
    agg_kernel<<<NB, 256, 0, stream>>>(payload, cursor, hWbf, el, er, out, N);
  }
}

// Round 5
// 180.530 us; speedup vs baseline: 2.4769x; 2.4769x over previous
//
#include <hip/hip_runtime.h>
#include <hip/hip_bf16.h>
#include <stdint.h>

#define IN_F 128
#define OUT_F 16
#define NEG_SLOPE 0.2f
#define LB_BITS 7               // bucket = 128 nodes (agg-tile granular scatter)
#define LB_NODES 128
#define NB 782                  // ceil(100000/128)
#define CAP 4608                // per-bucket capacity (mean 4092, +8 sigma)
#define SC_E 8192               // edges per scatter block (r1-proven)
#define PROJ_M 2                // nodes per thread in projection branch

// scatter LDS: hist/pref/gbase/rank (4*782*4=12512) + tsum (1024) + sortedP 32K
#define SMEM_BYTES (12512 + 1024 + SC_E * 4)

__device__ __forceinline__ float u2f(uint32_t u) {
  union { uint32_t i; float f; } c;
  c.i = u;
  return c.f;
}

// ---------------------------------------------------------------------------
// Fused proj + scatter, 256-thread blocks, r1-proven structure. NO
// __launch_bounds__ min-occupancy arg (r2/r4 both showed the clamp strangles
// the register allocator: VGPR 40/52 -> spills/stalls).
// Projection: 2 nodes per thread (r3-validated codegen, VGPR=60 no spill) —
// each wave-uniform W broadcast feeds 2 FMA streams, halving LDS-pipe
// pressure vs 1 node/thread. Scatter: byte-identical to r1 (54.9 us).
// ---------------------------------------------------------------------------
__global__ __launch_bounds__(256) void proj_scatter_kernel(
    const float* __restrict__ h, const float* __restrict__ W,
    const float* __restrict__ a_l, const float* __restrict__ a_r,
    const int* __restrict__ src, const int* __restrict__ dst,
    __hip_bfloat16* __restrict__ hWbf, float* __restrict__ el,
    float* __restrict__ er, int* __restrict__ cursor,
    uint32_t* __restrict__ payload, int N, int E, int scatBlocks) {
  __shared__ __align__(16) uint8_t smem[SMEM_BYTES];
  int t = threadIdx.x;

  if ((int)blockIdx.x < scatBlocks) {
    // ---------------- scatter branch (r1 verbatim) ----------------
    int* hist = (int*)smem;          // NB
    int* pref = hist + NB;
    int* gbase = pref + NB;
    int* rank = gbase + NB;
    int* tsum = rank + NB;           // 256
    uint32_t* sortedP = (uint32_t*)(tsum + 256);  // SC_E

    int start = blockIdx.x * SC_E;
    int end = min(E, start + SC_E);
    int cnt = end - start;

    for (int i = t; i < NB; i += 256) { hist[i] = 0; rank[i] = 0; }
    __syncthreads();

    const int4* d4 = (const int4*)(dst + start);
    int n4 = cnt >> 2;
    for (int i = t; i < n4; i += 256) {
      int4 d = d4[i];
      atomicAdd(&hist[d.x >> LB_BITS], 1);
      atomicAdd(&hist[d.y >> LB_BITS], 1);
      atomicAdd(&hist[d.z >> LB_BITS], 1);
      atomicAdd(&hist[d.w >> LB_BITS], 1);
    }
    for (int i = start + (n4 << 2) + t; i < end; i += 256)
      atomicAdd(&hist[dst[i] >> LB_BITS], 1);
    __syncthreads();

    // two-level exclusive prefix (4 buckets/thread) + global reservation
    {
      int b0 = t * 4;
      int s_loc = 0;
      if (b0 < NB) {
        int lim = min(b0 + 4, NB);
        for (int j = b0; j < lim; ++j) s_loc += hist[j];
      }
      tsum[t] = s_loc;
    }
    __syncthreads();
    {
      int pre = 0;
      for (int j = 0; j < t; ++j) pre += tsum[j];  // independent loads, pipelined
      int b0 = t * 4;
      if (b0 < NB) {
        int lim = min(b0 + 4, NB);
        int run = pre;
        for (int j = b0; j < lim; ++j) {
          pref[j] = run;
          int c = hist[j];
          run += c;
          gbase[j] = c ? atomicAdd(&cursor[j * 16], c) : 0;  // cursor pre-zeroed
        }
      }
    }
    __syncthreads();

    const int4* s4 = (const int4*)(src + start);
    for (int i = t; i < n4; i += 256) {
      int4 d = d4[i];
      int4 s = s4[i];
#pragma unroll
      for (int j = 0; j < 4; ++j) {
        int dd = j == 0 ? d.x : j == 1 ? d.y : j == 2 ? d.z : d.w;
        int ss = j == 0 ? s.x : j == 1 ? s.y : j == 2 ? s.z : s.w;
        int b = dd >> LB_BITS;
        int r = atomicAdd(&rank[b], 1);
        sortedP[pref[b] + r] =
            ((uint32_t)ss << LB_BITS) | (uint32_t)(dd & (LB_NODES - 1));
      }
    }
    for (int i = start + (n4 << 2) + t; i < end; i += 256) {
      int dd = dst[i];
      int b = dd >> LB_BITS;
      int r = atomicAdd(&rank[b], 1);
      sortedP[pref[b] + r] =
          ((uint32_t)src[i] << LB_BITS) | (uint32_t)(dd & (LB_NODES - 1));
    }
    __syncthreads();

    // write-out: 16-lane group per bucket run (runs avg ~10.5 entries)
    int g16 = t >> 4, l16 = t & 15;
    for (int b = g16; b < NB; b += 16) {
      int c = hist[b];
      if (c == 0) continue;
      int p0 = pref[b];
      int gb = gbase[b];
      size_t g0 = (size_t)b * CAP + (size_t)gb;
      for (int j = l16; j < c; j += 16)
        if (gb + j < CAP) payload[g0 + j] = sortedP[p0 + j];
    }
  } else {
    // ---------------- projection branch: 2 nodes per thread ----------------
    float* Ws = (float*)smem;  // 16*128 floats = 8 KB (wave-uniform broadcast)
    for (int i = t; i < OUT_F * IN_F; i += 256) Ws[i] = W[i];
    __syncthreads();

    int blk = (int)blockIdx.x - scatBlocks;
    int n0 = blk * (256 * PROJ_M) + t;
    int n1 = n0 + 256;
    if (n0 >= N) return;
    bool v1 = n1 < N;

    const float4* r0 = (const float4*)(h + (size_t)n0 * IN_F);
    const float4* r1 = (const float4*)(h + (size_t)(v1 ? n1 : n0) * IN_F);

    float acc0[OUT_F], acc1[OUT_F];
#pragma unroll
    for (int f = 0; f < OUT_F; ++f) { acc0[f] = 0.f; acc1[f] = 0.f; }

#pragma unroll 4
    for (int k = 0; k < IN_F / 4; ++k) {
      float4 h0 = r0[k];
      float4 h1 = r1[k];
#pragma unroll
      for (int f = 0; f < OUT_F; ++f) {
        float4 wv = ((const float4*)(Ws + f * IN_F))[k];  // uniform -> bcast
        acc0[f] += h0.x * wv.x + h0.y * wv.y + h0.z * wv.z + h0.w * wv.w;
        acc1[f] += h1.x * wv.x + h1.y * wv.y + h1.z * wv.z + h1.w * wv.w;
      }
    }

    union {
      unsigned short us[OUT_F];
      uint4 q[2];
    } pk;
#pragma unroll
    for (int f = 0; f < OUT_F; ++f) {
      __hip_bfloat16 b = __float2bfloat16(acc0[f]);
      pk.us[f] = *reinterpret_cast<unsigned short*>(&b);
    }
    uint4* dq0 = (uint4*)(hWbf + (size_t)n0 * OUT_F);
    dq0[0] = pk.q[0];
    dq0[1] = pk.q[1];

    float vl = 0.f, vr = 0.f;
#pragma unroll
    for (int f = 0; f < OUT_F; ++f) {
      vl += acc0[f] * a_l[f];
      vr += acc0[f] * a_r[f];
    }
    el[n0] = vl;
    er[n0] = vr;

    if (v1) {
#pragma unroll
      for (int f = 0; f < OUT_F; ++f) {
        __hip_bfloat16 b = __float2bfloat16(acc1[f]);
        pk.us[f] = *reinterpret_cast<unsigned short*>(&b);
      }
      uint4* dq1 = (uint4*)(hWbf + (size_t)n1 * OUT_F);
      dq1[0] = pk.q[0];
      dq1[1] = pk.q[1];
      float wl = 0.f, wr = 0.f;
#pragma unroll
      for (int f = 0; f < OUT_F; ++f) {
        wl += acc1[f] * a_l[f];
        wr += acc1[f] * a_r[f];
      }
      el[n1] = wl;
      er[n1] = wr;
    }
  }
}

// ---------------------------------------------------------------------------
// Aggregation: one block per 128-node bucket, 512 threads. Pass 1 histograms
// straight from global; pass 3 re-reads L2-hot payload and writes ONE u64
// (src|exp) LDS pair per edge (was 2x b32); pass 4 reads the pair back with
// one ds_read_b64 per lane-iteration (was 2x b32) -> halves LDS ops in the
// two hottest passes.
// ---------------------------------------------------------------------------
__global__ __launch_bounds__(512) void agg_kernel(
    const uint32_t* __restrict__ payload, const int* __restrict__ cursor,
    const __hip_bfloat16* __restrict__ hWbf, const float* __restrict__ el,
    const float* __restrict__ er, float* __restrict__ out, int N) {
  __shared__ __align__(16) uint2 pairs[CAP];  // 36.9 KB: (src<<7|dl, exp bits)
  __shared__ int hist[LB_NODES];
  __shared__ int pref[LB_NODES];
  __shared__ int rank[LB_NODES];
  __shared__ float erS[LB_NODES];

  int t = threadIdx.x;
  int b = blockIdx.x;
  size_t base = (size_t)b * CAP;
  int cnt = min(cursor[b * 16], CAP);
  int node0 = b << LB_BITS;

  if (t < LB_NODES) {
    hist[t] = 0;
    rank[t] = 0;
    int nd = node0 + t;
    erS[t] = nd < N ? er[nd] : 0.f;
  }
  __syncthreads();

  // pass 1: histogram straight from global (coalesced uint4)
  const uint4* pay4 = (const uint4*)(payload + base);  // CAP%4==0
  int n4 = (cnt + 3) >> 2;
  for (int i = t; i < n4; i += 512) {
    uint4 v = pay4[i];
    int i0 = i << 2;
    if (i0 + 0 < cnt) atomicAdd(&hist[v.x & (LB_NODES - 1)], 1);
    if (i0 + 1 < cnt) atomicAdd(&hist[v.y & (LB_NODES - 1)], 1);
    if (i0 + 2 < cnt) atomicAdd(&hist[v.z & (LB_NODES - 1)], 1);
    if (i0 + 3 < cnt) atomicAdd(&hist[v.w & (LB_NODES - 1)], 1);
  }
  __syncthreads();

  // pass 2: prefix over 128
  if (t < LB_NODES) {
    int s = 0;
    for (int j = 0; j < t; ++j) s += hist[j];
    pref[t] = s;
  }
  __syncthreads();

  // pass 3: place payload -> pairs[] with fused leaky+exp (payload L2-hot)
  for (int i = t; i < cnt; i += 512) {
    uint32_t p = payload[base + i];
    int dl = (int)(p & (LB_NODES - 1));
    int r = atomicAdd(&rank[dl], 1);
    float x = el[p >> LB_BITS] + erS[dl];
    x = x > 0.f ? x : NEG_SLOPE * x;
    pairs[pref[dl] + r] = make_uint2(p, __float_as_uint(__expf(x)));
  }
  __syncthreads();

  // pass 4: 4 lanes per node, one b64 LDS read + uint2 (4 bf16) gather per edge
  int g = t >> 2, f4 = t & 3;
  int node = node0 + g;
  if (node < N) {
    int k = pref[g];
    int kend = k + hist[g];
    float a0 = 0.f, a1 = 0.f, a2 = 0.f, a3 = 0.f, es = 0.f;
    const uint2* hw2 = (const uint2*)hWbf;
#pragma unroll 4
    for (; k < kend; ++k) {
      uint2 q = pairs[k];
      float ex = __uint_as_float(q.y);
      uint2 w = hw2[(size_t)(q.x >> LB_BITS) * 4 + f4];
      a0 += ex * u2f(w.x << 16);
      a1 += ex * u2f(w.x & 0xffff0000u);
      a2 += ex * u2f(w.y << 16);
      a3 += ex * u2f(w.y & 0xffff0000u);
      es += ex;
    }
    float inv = 1.0f / fmaxf(es, 1e-16f);
    float4 o = make_float4(a0 * inv, a1 * inv, a2 * inv, a3 * inv);
    ((float4*)(out + (size_t)node * OUT_F))[f4] = o;
  }
}

extern "C" void kernel_launch(void* const* d_in, const int* in_sizes, int n_in,
                              void* d_out, int out_size, void* d_ws, size_t ws_size,
                              hipStream_t stream) {
  const float* h   = (const float*)d_in[0];
  const int*   src = (const int*)d_in[1];
  const int*   dst = (const int*)d_in[2];
  const float* W   = (const float*)d_in[3];
  const float* a_l = (const float*)d_in[4];
  const float* a_r = (const float*)d_in[5];
  float* out = (float*)d_out;

  const int N = in_sizes[0] / IN_F;
  const int E = in_sizes[1];
  const int scatBlocks = (E + SC_E - 1) / SC_E;                    // 391
  const int projBlocks = (N + 256 * PROJ_M - 1) / (256 * PROJ_M);  // 196

  // ws: hWbf (bf16) | el | er | cursor | payload
  __hip_bfloat16* hWbf = (__hip_bfloat16*)d_ws;        // N*16 bf16 = 3.2 MB
  float* el = (float*)(hWbf + (size_t)N * OUT_F);      // N
  float* er = el + N;                                  // N
  int* cursor = (int*)(er + N);                        // NB*16 (line-strided)
  uint32_t* payload = (uint32_t*)(cursor + (size_t)NB * 16);  // NB*CAP = 14.4 MB

  hipMemsetAsync(cursor, 0, (size_t)NB * 16 * sizeof(int), stream);

  proj_scatter_kernel<<<scatBlocks + projBlocks, 256, 0, stream>>>(
      h, W, a_l, a_r, src, dst, hWbf, el, er, cursor, payload, N, E, scatBlocks);

  agg_kernel<<<NB, 512, 0, stream>>>(payload, cursor, hWbf, el, er, out, N);
}